// Round 10
// baseline (142.204 us; speedup 1.0000x reference)
//
#include <hip/hip_runtime.h>
#include <hip/hip_bf16.h>

#define B_ 8
#define T_ 2048
#define NROWS 16384

typedef __attribute__((ext_vector_type(16))) float f32x16;
typedef __attribute__((ext_vector_type(8))) short short8;
typedef __fp16 half2_t __attribute__((ext_vector_type(2)));
typedef __fp16 half8_t __attribute__((ext_vector_type(8)));

__device__ __forceinline__ unsigned int pkrtz(float a, float b) {
    half2_t h = __builtin_amdgcn_cvt_pkrtz(a, b);
    return __builtin_bit_cast(unsigned int, h);
}
// pack two fp32 into one dword of bf16 (truncate): low short = a, high = b
__device__ __forceinline__ unsigned int pkbf(float a, float b) {
    return __builtin_amdgcn_perm(__float_as_uint(b), __float_as_uint(a), 0x07060302u);
}
__device__ __forceinline__ float dot2(unsigned int a, unsigned int b, float c) {
    return __builtin_amdgcn_fdot2(__builtin_bit_cast(half2_t, a),
                                  __builtin_bit_cast(half2_t, b), c, false);
}
__device__ __forceinline__ float fast_exp2(float x) {
#if __has_builtin(__builtin_amdgcn_exp2f)
    return __builtin_amdgcn_exp2f(x);
#else
    return exp2f(x);
#endif
}

// ---------------------------------------------------------------------------
// Kernel 1: QKV projection (dot2) + cos(.+theta) + bf16 pack.
// Q,K stored [head][s][d]. V stored TRANSPOSED + pi-swizzled to global:
// vt[head64][half][d][s_sw] so attention reads PV A-frags directly (b128)
// with no LDS transpose. (Transpose done once here vs 16x per head in attn.)
// ---------------------------------------------------------------------------
__global__ __launch_bounds__(512, 2) void qkv_kernel(
    const float* __restrict__ x,
    const float* __restrict__ Wq, const float* __restrict__ bq,
    const float* __restrict__ Wk, const float* __restrict__ bk,
    const float* __restrict__ Wv, const float* __restrict__ bv,
    const float* __restrict__ theta_attn,
    unsigned short* __restrict__ qb, unsigned short* __restrict__ kbuf,
    unsigned short* __restrict__ vt)
{
    __shared__ unsigned int xpk[32 * 66];
    __shared__ unsigned int wpk[32 * 196];
    __shared__ unsigned int outs[6144];       // [24 bh][64 r][4 dw]
    const int tid = threadIdx.x;
    const int n0 = blockIdx.x * 64;

    #pragma unroll
    for (int t = 0; t < 2; t++) {
        int fi = tid + t * 512;
        float4 v = ((const float4*)(x + (size_t)n0 * 64))[fi];
        int r = fi >> 4, k0 = (fi & 15) * 4;
        xpk[(k0 >> 1) * 66 + r] = pkrtz(v.x, v.y);
        xpk[((k0 >> 1) + 1) * 66 + r] = pkrtz(v.z, v.w);
    }
    const float* Wm[3] = {Wq, Wk, Wv};
    #pragma unroll
    for (int t = 0; t < 6; t++) {
        int fi = tid + t * 512;
        int m = fi >> 10, j = (fi >> 4) & 63, k0 = (fi & 15) * 4;
        float4 v = ((const float4*)Wm[m])[fi & 1023];
        wpk[(k0 >> 1) * 196 + m * 64 + j] = pkrtz(v.x, v.y);
        wpk[((k0 >> 1) + 1) * 196 + m * 64 + j] = pkrtz(v.z, v.w);
    }
    __syncthreads();

    const int r0 = (tid & 31) * 2;
    const int c0 = (tid >> 5) * 12;
    float acc[2][12] = {};
    #pragma unroll 8
    for (int kp = 0; kp < 32; kp++) {
        uint2 a = *(const uint2*)&xpk[kp * 66 + r0];
        uint4 b0 = *(const uint4*)&wpk[kp * 196 + c0];
        uint4 b1 = *(const uint4*)&wpk[kp * 196 + c0 + 4];
        uint4 b2 = *(const uint4*)&wpk[kp * 196 + c0 + 8];
        unsigned int bb[12] = {b0.x, b0.y, b0.z, b0.w,
                               b1.x, b1.y, b1.z, b1.w,
                               b2.x, b2.y, b2.z, b2.w};
        #pragma unroll
        for (int j = 0; j < 12; j++) {
            acc[0][j] = dot2(a.x, bb[j], acc[0][j]);
            acc[1][j] = dot2(a.y, bb[j], acc[1][j]);
        }
    }

    {
        const float th = *theta_attn;
        const float QS = 0.51006980f;         // log2(e)/sqrt(8)
        const float* biasp[3] = {bq, bk, bv};
        float bcol[12];
        #pragma unroll
        for (int j = 0; j < 12; j++) {
            int c = c0 + j;
            bcol[j] = biasp[c >> 6][c & 63];
        }
        #pragma unroll
        for (int i = 0; i < 2; i++) {
            float vals[12];
            #pragma unroll
            for (int j = 0; j < 12; j++) {
                float v = __cosf(acc[i][j] + bcol[j] + th);
                vals[j] = ((c0 + j) >> 6) == 0 ? v * QS : v;
            }
            int row = r0 + i;
            #pragma unroll
            for (int t = 0; t < 6; t++) {
                int c = c0 + 2 * t;
                outs[(c >> 3) * 256 + row * 4 + ((c & 7) >> 1)] = pkbf(vals[2*t], vals[2*t+1]);
            }
        }
    }
    __syncthreads();

    // ---- Q,K: coalesced uint4 stores ([head][s][d]) ----
    unsigned short* outp2[2] = {qb, kbuf};
    #pragma unroll
    for (int t = 0; t < 2; t++) {
        int fi = tid + t * 512;               // 1024 uint4: bh 0..15
        int bh = fi >> 6, r2 = fi & 63;
        int m = bh >> 3, hI = bh & 7;
        uint4 v = *(const uint4*)&outs[4 * fi];
        int n = n0 + r2;
        unsigned short* dst = outp2[m] +
            ((size_t)((n >> 11) * 8 + hI) * 2048 + (n & 2047)) * 8;
        *(uint4*)dst = v;
    }
    // ---- V: transposed + pi-swizzled store: vt[(head64*2+half)*8+d][s] ----
    {
        int head = tid >> 6, d = (tid >> 3) & 7, j = tid & 7;
        int bh = 16 + head, dw = d >> 1, hb = d & 1;
        const unsigned short* ob = (const unsigned short*)outs;
        union { uint4 u; unsigned short us[8]; } pk;
        #pragma unroll
        for (int e = 0; e < 8; e++) {
            int sp = 8 * j + e;
            int r = (sp & ~12) | ((sp & 4) << 1) | ((sp & 8) >> 1);  // pi (involution)
            pk.us[e] = ob[(bh * 256 + r * 4 + dw) * 2 + hb];
        }
        int bI = n0 >> 11, tI0 = n0 & 2047;
        int half = tI0 >> 10, s0v = tI0 & 1023;
        size_t idx = ((((size_t)(bI * 8 + head) * 2 + half) * 8 + d) * 1024 + s0v + 8 * j);
        *(uint4*)(vt + idx) = pk.u;
    }
}

// ---------------------------------------------------------------------------
// Kernel 2: flash attention, S^T form, 32x32x16 bf16 MFMA. R8 tiling
// (32 q/wave, 1024 blocks, 4 blocks/CU) restored. V is NOT staged in LDS:
// PV A-frags come straight from the pre-transposed/swizzled vt in global
// (L1/L2-hot; masked b128), ones rows from a register constant.
// FIX: rows >=8 of A are all-ones so C rows 8 AND 12 both hold lsum ->
// tot = 2*lsum after the h-swap; inv = 2/tot (R7-R9 silently halved attn).
// ---------------------------------------------------------------------------
__global__ __launch_bounds__(256, 4) void attn_kernel(
    const unsigned short* __restrict__ qb,
    const unsigned short* __restrict__ kbuf,
    const unsigned short* __restrict__ vt,
    float* __restrict__ attn)
{
    __shared__ __align__(16) unsigned short Ks[1024 * 8];  // K rows bf16 (16 KB)
    const int tid = threadIdx.x;
    const int head = blockIdx.x >> 4;         // b*8 + h
    const int qblk = blockIdx.x & 15;
    const size_t hoff = (size_t)head * T_ * 8;
    const int wave = tid >> 6, lane = tid & 63;
    const int col = lane & 31, h = lane >> 5;
    const int q0 = qblk * 128 + wave * 32;

    const short8 z8 = {0, 0, 0, 0, 0, 0, 0, 0};
    union { uint4 u; short8 s; } onesu;
    onesu.u = make_uint4(0x3f803f80u, 0x3f803f80u, 0x3f803f80u, 0x3f803f80u);
    const short8 ones8 = onesu.s;

    short8 bqf = z8;                          // Q B-frag: n=q, k=d (h=1 lanes 0)
    if (h == 0) bqf = *(const short8*)(qb + hoff + (size_t)(q0 + col) * 8);

    f32x16 oacc = {0.f,0.f,0.f,0.f,0.f,0.f,0.f,0.f,0.f,0.f,0.f,0.f,0.f,0.f,0.f,0.f};
    const f32x16 z16 = oacc;
    short8 ak = z8;                           // loop-carried; h=1 lanes stay 0

    for (int half = 0; half < 2; half++) {
        __syncthreads();
        {
            const uint4* kg = (const uint4*)(kbuf + hoff + (size_t)half * 1024 * 8);
            #pragma unroll
            for (int it = 0; it < 4; it++) {
                int s = tid + it * 256;
                ((uint4*)Ks)[s] = kg[s];
            }
        }
        __syncthreads();

        const unsigned short* vrow =
            vt + (((size_t)head * 2 + half) * 8 + col) * 1024 + 8 * h;

        for (int s0 = 0; s0 < 1024; s0 += 32) {
            short8 av0 = ones8, av1 = ones8;  // rows >=8: ones (lsum rows)
            if (col < 8) {
                av0 = *(const short8*)&vrow[s0];
                av1 = *(const short8*)&vrow[s0 + 16];
            }
            if (h == 0) ak = *(const short8*)&Ks[(s0 + col) * 8];
            f32x16 S = __builtin_amdgcn_mfma_f32_32x32x16_bf16(ak, bqf, z16, 0, 0, 0);
            {
                union { unsigned int u[4]; short8 s; } bp;
                bp.u[0] = pkbf(fast_exp2(S[0]), fast_exp2(S[1]));
                bp.u[1] = pkbf(fast_exp2(S[2]), fast_exp2(S[3]));
                bp.u[2] = pkbf(fast_exp2(S[4]), fast_exp2(S[5]));
                bp.u[3] = pkbf(fast_exp2(S[6]), fast_exp2(S[7]));
                oacc = __builtin_amdgcn_mfma_f32_32x32x16_bf16(av0, bp.s, oacc, 0, 0, 0);
                bp.u[0] = pkbf(fast_exp2(S[8]),  fast_exp2(S[9]));
                bp.u[1] = pkbf(fast_exp2(S[10]), fast_exp2(S[11]));
                bp.u[2] = pkbf(fast_exp2(S[12]), fast_exp2(S[13]));
                bp.u[3] = pkbf(fast_exp2(S[14]), fast_exp2(S[15]));
                oacc = __builtin_amdgcn_mfma_f32_32x32x16_bf16(av1, bp.s, oacc, 0, 0, 0);
            }
        }
    }

    float tot = oacc[4];                      // row 8 (h=0) / row 12 (h=1): both lsum
    tot += __shfl_xor(tot, 32);               // tot = 2 * lsum on every lane
    const float inv = 2.0f / tot;
    const int bI = head >> 3, hI = head & 7;
    const int q = q0 + col;
    #pragma unroll
    for (int rr = 0; rr < 4; rr++) {          // O^T regs 0-3: d = 4h + rr
        int d = 4 * h + rr;
        attn[((size_t)bI * 2048 + q) * 64 + hI * 8 + d] = oacc[rr] * inv;
    }
}

// ---------------------------------------------------------------------------
// Kernel 3 (fused tail, MFMA-based) -- unchanged from round 8.
// ---------------------------------------------------------------------------
__global__ __launch_bounds__(512, 4) void tail_kernel(
    const float* __restrict__ attn, const float* __restrict__ x,
    const float* __restrict__ Wo, const float* __restrict__ bo,
    const float* __restrict__ g1, const float* __restrict__ be1,
    const float* __restrict__ theta_ffn,
    const float* __restrict__ W1, const float* __restrict__ b1,
    const float* __restrict__ W2, const float* __restrict__ b2,
    const float* __restrict__ g2, const float* __restrict__ be2,
    float* __restrict__ outp)
{
    __shared__ unsigned int smem[15744];
    const int tid = threadIdx.x;
    const int lane = tid & 63;
    const int wave = tid >> 6;
    const int h = lane >> 5;
    const int n0 = blockIdx.x * 32;
    const int mrow = tid >> 4;
    const int c0 = (tid & 15) * 4;

    unsigned int* const W1p = smem;
    unsigned int* const W2p = smem;
    unsigned int* const Atp = smem + 9216;
    unsigned int* const qoutp = smem + 9216;
    unsigned int* const Wop = smem + 10368;
    unsigned int* const hrowp = smem + 10368;
    float* const Yf = (float*)(smem + 12672);
    float* const Y2a = (float*)(smem + 14592);
    float* const Y2b = (float*)(smem + 8448);

    const f32x16 z16 = {0.f,0.f,0.f,0.f,0.f,0.f,0.f,0.f,0.f,0.f,0.f,0.f,0.f,0.f,0.f,0.f};

    float4 atv = ((const float4*)(attn + (size_t)n0 * 64))[tid];
    float4 wo0 = ((const float4*)Wo)[tid];
    float4 wo1 = ((const float4*)Wo)[tid + 512];
    float4 xv = *(const float4*)(x + (size_t)(n0 + mrow) * 64 + c0);
    float4 w1r[8];
    #pragma unroll
    for (int t = 0; t < 8; t++) w1r[t] = ((const float4*)W1)[tid + t * 512];

    {
        int r = tid >> 4, k0 = (tid & 15) * 4;
        uint2 a2 = make_uint2(pkrtz(atv.x, atv.y), pkrtz(atv.z, atv.w));
        *(uint2*)&Atp[r * 36 + (k0 >> 1)] = a2;
        uint2 wa = make_uint2(pkrtz(wo0.x, wo0.y), pkrtz(wo0.z, wo0.w));
        *(uint2*)&Wop[r * 36 + (k0 >> 1)] = wa;
        int fi = tid + 512;
        int e1 = fi >> 4, k1 = (fi & 15) * 4;
        uint2 wb = make_uint2(pkrtz(wo1.x, wo1.y), pkrtz(wo1.z, wo1.w));
        *(uint2*)&Wop[e1 * 36 + (k1 >> 1)] = wb;
    }
    __syncthreads();

    #pragma unroll
    for (int t = 0; t < 8; t++) {
        int fi = tid + t * 512;
        int f = fi >> 4, k0 = (fi & 15) * 4;
        uint2 w2 = make_uint2(pkrtz(w1r[t].x, w1r[t].y), pkrtz(w1r[t].z, w1r[t].w));
        *(uint2*)&W1p[f * 36 + (k0 >> 1)] = w2;
    }

    if (wave < 2) {
        const int colo = wave * 32 + (lane & 31);
        f32x16 acc = z16;
        #pragma unroll
        for (int kk = 0; kk < 4; kk++) {
            half8_t a = __builtin_bit_cast(half8_t,
                *(const uint4*)&Atp[(lane & 31) * 36 + kk * 8 + h * 4]);
            half8_t b = __builtin_bit_cast(half8_t,
                *(const uint4*)&Wop[colo * 36 + kk * 8 + h * 4]);
            acc = __builtin_amdgcn_mfma_f32_32x32x16_f16(a, b, acc, 0, 0, 0);
        }
        float bov = bo[colo];
        #pragma unroll
        for (int reg = 0; reg < 16; reg++) {
            int rr = (reg & 3) + 8 * (reg >> 2) + 4 * h;
            Yf[rr * 68 + colo] = acc[reg] + bov;
        }
    }
    __syncthreads();

    float x1v[4];
    {
        float4 yv = *(const float4*)&Yf[mrow * 68 + c0];
        float vv[4] = {xv.x + yv.x, xv.y + yv.y, xv.z + yv.z, xv.w + yv.w};
        float s1 = vv[0] + vv[1] + vv[2] + vv[3];
        float s2 = vv[0]*vv[0] + vv[1]*vv[1] + vv[2]*vv[2] + vv[3]*vv[3];
        #pragma unroll
        for (int m = 1; m <= 8; m <<= 1) {
            s1 += __shfl_xor(s1, m);
            s2 += __shfl_xor(s2, m);
        }
        float mean = s1 * 0.015625f;
        float rstd = rsqrtf(s2 * 0.015625f - mean * mean + 1e-5f);
        float4 g14 = *(const float4*)&g1[c0];
        float4 be14 = *(const float4*)&be1[c0];
        float gg[4] = {g14.x, g14.y, g14.z, g14.w};
        float eb[4] = {be14.x, be14.y, be14.z, be14.w};
        float cth = __cosf(*theta_ffn);
        float qv[4];
        #pragma unroll
        for (int j = 0; j < 4; j++) {
            x1v[j] = (vv[j] - mean) * rstd * gg[j] + eb[j];
            qv[j] = __cosf(x1v[j]) * cth;
        }
        uint2 q2 = make_uint2(pkrtz(qv[0], qv[1]), pkrtz(qv[2], qv[3]));
        *(uint2*)&qoutp[mrow * 36 + (c0 >> 1)] = q2;
    }
    __syncthreads();

    float4 w2r[8];
    #pragma unroll
    for (int t = 0; t < 8; t++) w2r[t] = ((const float4*)W2)[tid + t * 512];

    {
        const int fl = lane & 31;
        f32x16 acc = z16;
        #pragma unroll
        for (int kk = 0; kk < 4; kk++) {
            half8_t a = __builtin_bit_cast(half8_t,
                *(const uint4*)&W1p[(wave * 32 + fl) * 36 + kk * 8 + h * 4]);
            half8_t b = __builtin_bit_cast(half8_t,
                *(const uint4*)&qoutp[fl * 36 + kk * 8 + h * 4]);
            acc = __builtin_amdgcn_mfma_f32_32x32x16_f16(a, b, acc, 0, 0, 0);
        }
        const int row = lane & 31;
        #pragma unroll
        for (int q = 0; q < 4; q++) {
            int fb = wave * 32 + 8 * q + 4 * h;
            float4 b1v = *(const float4*)&b1[fb];
            float h0 = fmaxf(acc[4*q+0] + b1v.x, 0.f);
            float h1 = fmaxf(acc[4*q+1] + b1v.y, 0.f);
            float h2 = fmaxf(acc[4*q+2] + b1v.z, 0.f);
            float h3 = fmaxf(acc[4*q+3] + b1v.w, 0.f);
            uint2 hp = make_uint2(pkrtz(h0, h1), pkrtz(h2, h3));
            *(uint2*)&hrowp[row * 132 + (fb >> 1)] = hp;
        }
    }
    __syncthreads();

    #pragma unroll
    for (int t = 0; t < 8; t++) {
        int fi = tid + t * 512;
        int e = fi >> 6, k0 = (fi & 63) * 4;
        uint2 w2 = make_uint2(pkrtz(w2r[t].x, w2r[t].y), pkrtz(w2r[t].z, w2r[t].w));
        *(uint2*)&W2p[e * 132 + (k0 >> 1)] = w2;
    }
    __syncthreads();

    if (wave < 2) {
        const int colo = wave * 32 + (lane & 31);
        f32x16 acc = z16;
        #pragma unroll
        for (int kk = 0; kk < 16; kk++) {
            half8_t a = __builtin_bit_cast(half8_t,
                *(const uint4*)&hrowp[(lane & 31) * 132 + kk * 8 + h * 4]);
            half8_t b = __builtin_bit_cast(half8_t,
                *(const uint4*)&W2p[colo * 132 + kk * 8 + h * 4]);
            acc = __builtin_amdgcn_mfma_f32_32x32x16_f16(a, b, acc, 0, 0, 0);
        }
        float b2v = b2[colo];
        float* Ydst = wave ? Y2b : Y2a;
        const int cl = lane & 31;
        #pragma unroll
        for (int reg = 0; reg < 16; reg++) {
            int rr = (reg & 3) + 8 * (reg >> 2) + 4 * h;
            Ydst[rr * 36 + cl] = acc[reg] + b2v;
        }
    }
    __syncthreads();

    {
        float4 fv = (c0 < 32) ? *(const float4*)&Y2a[mrow * 36 + c0]
                              : *(const float4*)&Y2b[mrow * 36 + (c0 - 32)];
        float vv[4] = {x1v[0] + fv.x, x1v[1] + fv.y, x1v[2] + fv.z, x1v[3] + fv.w};
        float s1 = vv[0] + vv[1] + vv[2] + vv[3];
        float s2 = vv[0]*vv[0] + vv[1]*vv[1] + vv[2]*vv[2] + vv[3]*vv[3];
        #pragma unroll
        for (int m = 1; m <= 8; m <<= 1) {
            s1 += __shfl_xor(s1, m);
            s2 += __shfl_xor(s2, m);
        }
        float mean = s1 * 0.015625f;
        float rstd = rsqrtf(s2 * 0.015625f - mean * mean + 1e-5f);
        float4 g24 = *(const float4*)&g2[c0];
        float4 be24 = *(const float4*)&be2[c0];
        float4 o;
        o.x = (vv[0] - mean) * rstd * g24.x + be24.x;
        o.y = (vv[1] - mean) * rstd * g24.y + be24.y;
        o.z = (vv[2] - mean) * rstd * g24.z + be24.z;
        o.w = (vv[3] - mean) * rstd * g24.w + be24.w;
        *(float4*)(outp + (size_t)(n0 + mrow) * 64 + c0) = o;
    }
}

// ---------------------------------------------------------------------------
extern "C" void kernel_launch(void* const* d_in, const int* in_sizes, int n_in,
                              void* d_out, int out_size, void* d_ws, size_t ws_size,
                              hipStream_t stream)
{
    const float* x   = (const float*)d_in[0];
    const float* Wq  = (const float*)d_in[1];
    const float* bq  = (const float*)d_in[2];
    const float* Wk  = (const float*)d_in[3];
    const float* bk  = (const float*)d_in[4];
    const float* Wv  = (const float*)d_in[5];
    const float* bv  = (const float*)d_in[6];
    const float* Wo  = (const float*)d_in[7];
    const float* bo  = (const float*)d_in[8];
    const float* tha = (const float*)d_in[9];
    const float* thf = (const float*)d_in[10];
    const float* W1  = (const float*)d_in[11];
    const float* b1  = (const float*)d_in[12];
    const float* W2  = (const float*)d_in[13];
    const float* b2  = (const float*)d_in[14];
    const float* g1  = (const float*)d_in[15];
    const float* be1 = (const float*)d_in[16];
    const float* g2  = (const float*)d_in[17];
    const float* be2 = (const float*)d_in[18];

    // workspace: qb(2M) kb(2M) vt(2M, transposed+swizzled) attn(4M)
    char* wsb = (char*)d_ws;
    unsigned short* qbp = (unsigned short*)(wsb);
    unsigned short* kbp = (unsigned short*)(wsb + (2u << 20));
    unsigned short* vtp = (unsigned short*)(wsb + (4u << 20));
    float* attn = (float*)(wsb + (6u << 20));

    qkv_kernel<<<256, 512, 0, stream>>>(x, Wq, bq, Wk, bk, Wv, bv, tha, qbp, kbp, vtp);
    attn_kernel<<<1024, 256, 0, stream>>>(qbp, kbp, vtp, attn);
    tail_kernel<<<512, 512, 0, stream>>>(attn, x, Wo, bo, g1, be1, thf,
                                         W1, b1, W2, b2, g2, be2, (float*)d_out);
}

// Round 12
// 139.533 us; speedup vs baseline: 1.0191x; 1.0191x over previous
//
#include <hip/hip_runtime.h>
#include <hip/hip_bf16.h>

#define B_ 8
#define T_ 2048
#define NROWS 16384

typedef __attribute__((ext_vector_type(16))) float f32x16;
typedef __attribute__((ext_vector_type(8))) short short8;
typedef __fp16 half2_t __attribute__((ext_vector_type(2)));
typedef __fp16 half8_t __attribute__((ext_vector_type(8)));

__device__ __forceinline__ unsigned int pkrtz(float a, float b) {
    half2_t h = __builtin_amdgcn_cvt_pkrtz(a, b);
    return __builtin_bit_cast(unsigned int, h);
}
// pack two fp32 into one dword of bf16 (truncate): low short = a, high = b
__device__ __forceinline__ unsigned int pkbf(float a, float b) {
    return __builtin_amdgcn_perm(__float_as_uint(b), __float_as_uint(a), 0x07060302u);
}
__device__ __forceinline__ float dot2(unsigned int a, unsigned int b, float c) {
    return __builtin_amdgcn_fdot2(__builtin_bit_cast(half2_t, a),
                                  __builtin_bit_cast(half2_t, b), c, false);
}
__device__ __forceinline__ float fast_exp2(float x) {
#if __has_builtin(__builtin_amdgcn_exp2f)
    return __builtin_amdgcn_exp2f(x);
#else
    return exp2f(x);
#endif
}

// ---------------------------------------------------------------------------
// Kernel 1: QKV projection (dot2) + cos(.+theta) + bf16 pack to [B,H,T,DK].
// (R8 known-good form.)
// ---------------------------------------------------------------------------
__global__ __launch_bounds__(512, 2) void qkv_kernel(
    const float* __restrict__ x,
    const float* __restrict__ Wq, const float* __restrict__ bq,
    const float* __restrict__ Wk, const float* __restrict__ bk,
    const float* __restrict__ Wv, const float* __restrict__ bv,
    const float* __restrict__ theta_attn,
    unsigned short* __restrict__ qb, unsigned short* __restrict__ kbuf,
    unsigned short* __restrict__ vbuf)
{
    __shared__ unsigned int xpk[32 * 66];
    __shared__ unsigned int wpk[32 * 196];
    __shared__ unsigned int outs[6144];
    const int tid = threadIdx.x;
    const int n0 = blockIdx.x * 64;

    #pragma unroll
    for (int t = 0; t < 2; t++) {
        int fi = tid + t * 512;
        float4 v = ((const float4*)(x + (size_t)n0 * 64))[fi];
        int r = fi >> 4, k0 = (fi & 15) * 4;
        xpk[(k0 >> 1) * 66 + r] = pkrtz(v.x, v.y);
        xpk[((k0 >> 1) + 1) * 66 + r] = pkrtz(v.z, v.w);
    }
    const float* Wm[3] = {Wq, Wk, Wv};
    #pragma unroll
    for (int t = 0; t < 6; t++) {
        int fi = tid + t * 512;
        int m = fi >> 10, j = (fi >> 4) & 63, k0 = (fi & 15) * 4;
        float4 v = ((const float4*)Wm[m])[fi & 1023];
        wpk[(k0 >> 1) * 196 + m * 64 + j] = pkrtz(v.x, v.y);
        wpk[((k0 >> 1) + 1) * 196 + m * 64 + j] = pkrtz(v.z, v.w);
    }
    __syncthreads();

    const int r0 = (tid & 31) * 2;
    const int c0 = (tid >> 5) * 12;
    float acc[2][12] = {};
    #pragma unroll 8
    for (int kp = 0; kp < 32; kp++) {
        uint2 a = *(const uint2*)&xpk[kp * 66 + r0];
        uint4 b0 = *(const uint4*)&wpk[kp * 196 + c0];
        uint4 b1 = *(const uint4*)&wpk[kp * 196 + c0 + 4];
        uint4 b2 = *(const uint4*)&wpk[kp * 196 + c0 + 8];
        unsigned int bb[12] = {b0.x, b0.y, b0.z, b0.w,
                               b1.x, b1.y, b1.z, b1.w,
                               b2.x, b2.y, b2.z, b2.w};
        #pragma unroll
        for (int j = 0; j < 12; j++) {
            acc[0][j] = dot2(a.x, bb[j], acc[0][j]);
            acc[1][j] = dot2(a.y, bb[j], acc[1][j]);
        }
    }

    {
        const float th = *theta_attn;
        const float QS = 0.51006980f;         // log2(e)/sqrt(8)
        const float* biasp[3] = {bq, bk, bv};
        float bcol[12];
        #pragma unroll
        for (int j = 0; j < 12; j++) {
            int c = c0 + j;
            bcol[j] = biasp[c >> 6][c & 63];
        }
        #pragma unroll
        for (int i = 0; i < 2; i++) {
            float vals[12];
            #pragma unroll
            for (int j = 0; j < 12; j++) {
                float v = __cosf(acc[i][j] + bcol[j] + th);
                vals[j] = ((c0 + j) >> 6) == 0 ? v * QS : v;
            }
            int row = r0 + i;
            #pragma unroll
            for (int t = 0; t < 6; t++) {
                int c = c0 + 2 * t;
                outs[(c >> 3) * 256 + row * 4 + ((c & 7) >> 1)] = pkbf(vals[2*t], vals[2*t+1]);
            }
        }
    }
    __syncthreads();

    unsigned short* outp3[3] = {qb, kbuf, vbuf};
    #pragma unroll
    for (int t = 0; t < 3; t++) {
        int fi = tid + t * 512;
        int bh = fi >> 6, r2 = fi & 63;
        int m = bh >> 3, hI = bh & 7;
        uint4 v = *(const uint4*)&outs[4 * fi];
        int n = n0 + r2;
        unsigned short* dst = outp3[m] +
            ((size_t)((n >> 11) * 8 + hI) * 2048 + (n & 2047)) * 8;
        *(uint4*)dst = v;
    }
}

// ---------------------------------------------------------------------------
// Kernel 2: flash attention, S^T form, 32x32x16 bf16 MFMA. R8 known-good
// structure (V in LDS, 32 q/wave, 1024 blocks, 4 blocks/CU) with the
// CORRECTED softmax scale: A-rows >=8 are all ones, so C rows 8 AND 12 both
// hold Sum_p -> after shfl_xor(32), tot = 2*Sum_p on every lane; inv = 2/tot
// (R8 divided by tot, silently halving attention -- caught in R10).
// ---------------------------------------------------------------------------
__global__ __launch_bounds__(256, 4) void attn_kernel(
    const unsigned short* __restrict__ qb,
    const unsigned short* __restrict__ kbuf,
    const unsigned short* __restrict__ vbuf,
    float* __restrict__ attn)
{
    __shared__ __align__(16) unsigned short Ks[1024 * 8];  // K rows bf16 (16 KB)
    __shared__ __align__(16) unsigned short Vt[9 * 1032];  // V^T bf16 (+ones row 8)
    const int tid = threadIdx.x;
    const int head = blockIdx.x >> 4;         // b*8 + h
    const int qblk = blockIdx.x & 15;
    const size_t hoff = (size_t)head * T_ * 8;
    const int wave = tid >> 6, lane = tid & 63;
    const int col = lane & 31, h = lane >> 5;
    const int q0 = qblk * 128 + wave * 32;

    const short8 z8 = {0, 0, 0, 0, 0, 0, 0, 0};
    short8 bqf = z8;                          // Q B-frag: n=q, k=d (h=1 lanes stay 0)
    if (h == 0) bqf = *(const short8*)(qb + hoff + (size_t)(q0 + col) * 8);

    // ones row (d=8): C rows 8 and 12 accumulate Sum_p
    if (tid < 128)
        ((uint4*)(Vt + 8 * 1032))[tid] =
            make_uint4(0x3f803f80u, 0x3f803f80u, 0x3f803f80u, 0x3f803f80u);

    f32x16 oacc = {0.f,0.f,0.f,0.f,0.f,0.f,0.f,0.f,0.f,0.f,0.f,0.f,0.f,0.f,0.f,0.f};
    const f32x16 z16 = oacc;
    const unsigned short* vbase = &Vt[(col < 9 ? col : 8) * 1032 + 8 * h];
    short8 ak = z8;                           // loop-carried; h=1 lanes stay 0

    for (int half = 0; half < 2; half++) {
        __syncthreads();
        {
            const uint4* kg = (const uint4*)(kbuf + hoff + (size_t)half * 1024 * 8);
            const uint4* vg = (const uint4*)(vbuf + hoff + (size_t)half * 1024 * 8);
            #pragma unroll
            for (int it = 0; it < 4; it++) {
                int s = tid + it * 256;
                ((uint4*)Ks)[s] = kg[s];
                union { uint4 u; unsigned short us[8]; } cv;
                cv.u = vg[s];
                int sp = (s & ~12) | ((s & 4) << 1) | ((s & 8) >> 1);  // pi swizzle
                #pragma unroll
                for (int d = 0; d < 8; d++) Vt[d * 1032 + sp] = cv.us[d];
            }
        }
        __syncthreads();

        for (int s0 = 0; s0 < 1024; s0 += 32) {
            if (h == 0) ak = *(const short8*)&Ks[(s0 + col) * 8];
            f32x16 S = __builtin_amdgcn_mfma_f32_32x32x16_bf16(ak, bqf, z16, 0, 0, 0);
            #pragma unroll
            for (int g = 0; g < 2; g++) {     // keys [s0+16g, s0+16g+16)
                const int o = g * 8;
                union { unsigned int u[4]; short8 s; } bp;
                bp.u[0] = pkbf(fast_exp2(S[o+0]), fast_exp2(S[o+1]));
                bp.u[1] = pkbf(fast_exp2(S[o+2]), fast_exp2(S[o+3]));
                bp.u[2] = pkbf(fast_exp2(S[o+4]), fast_exp2(S[o+5]));
                bp.u[3] = pkbf(fast_exp2(S[o+6]), fast_exp2(S[o+7]));
                short8 av = *(const short8*)&vbase[s0 + g * 16];  // one b128
                oacc = __builtin_amdgcn_mfma_f32_32x32x16_bf16(av, bp.s, oacc, 0, 0, 0);
            }
        }
    }

    float tot = oacc[4];                      // row 8 (h=0) / row 12 (h=1): both Sum_p
    tot += __shfl_xor(tot, 32);               // tot = 2 * Sum_p on every lane
    const float inv = 2.0f / tot;             // CORRECT scale (R8 used 1/tot)
    const int bI = head >> 3, hI = head & 7;
    const int q = q0 + col;
    #pragma unroll
    for (int rr = 0; rr < 4; rr++) {          // O^T regs 0-3: d = 4h + rr
        int d = 4 * h + rr;
        attn[((size_t)bI * 2048 + q) * 64 + hI * 8 + d] = oacc[rr] * inv;
    }
}

// ---------------------------------------------------------------------------
// Kernel 3 (fused tail, MFMA-based) -- R8 known-good form.
// ---------------------------------------------------------------------------
__global__ __launch_bounds__(512, 4) void tail_kernel(
    const float* __restrict__ attn, const float* __restrict__ x,
    const float* __restrict__ Wo, const float* __restrict__ bo,
    const float* __restrict__ g1, const float* __restrict__ be1,
    const float* __restrict__ theta_ffn,
    const float* __restrict__ W1, const float* __restrict__ b1,
    const float* __restrict__ W2, const float* __restrict__ b2,
    const float* __restrict__ g2, const float* __restrict__ be2,
    float* __restrict__ outp)
{
    __shared__ unsigned int smem[15744];
    const int tid = threadIdx.x;
    const int lane = tid & 63;
    const int wave = tid >> 6;
    const int h = lane >> 5;
    const int n0 = blockIdx.x * 32;
    const int mrow = tid >> 4;
    const int c0 = (tid & 15) * 4;

    unsigned int* const W1p = smem;
    unsigned int* const W2p = smem;
    unsigned int* const Atp = smem + 9216;
    unsigned int* const qoutp = smem + 9216;
    unsigned int* const Wop = smem + 10368;
    unsigned int* const hrowp = smem + 10368;
    float* const Yf = (float*)(smem + 12672);
    float* const Y2a = (float*)(smem + 14592);
    float* const Y2b = (float*)(smem + 8448);

    const f32x16 z16 = {0.f,0.f,0.f,0.f,0.f,0.f,0.f,0.f,0.f,0.f,0.f,0.f,0.f,0.f,0.f,0.f};

    float4 atv = ((const float4*)(attn + (size_t)n0 * 64))[tid];
    float4 wo0 = ((const float4*)Wo)[tid];
    float4 wo1 = ((const float4*)Wo)[tid + 512];
    float4 xv = *(const float4*)(x + (size_t)(n0 + mrow) * 64 + c0);
    float4 w1r[8];
    #pragma unroll
    for (int t = 0; t < 8; t++) w1r[t] = ((const float4*)W1)[tid + t * 512];

    {
        int r = tid >> 4, k0 = (tid & 15) * 4;
        uint2 a2 = make_uint2(pkrtz(atv.x, atv.y), pkrtz(atv.z, atv.w));
        *(uint2*)&Atp[r * 36 + (k0 >> 1)] = a2;
        uint2 wa = make_uint2(pkrtz(wo0.x, wo0.y), pkrtz(wo0.z, wo0.w));
        *(uint2*)&Wop[r * 36 + (k0 >> 1)] = wa;
        int fi = tid + 512;
        int e1 = fi >> 4, k1 = (fi & 15) * 4;
        uint2 wb = make_uint2(pkrtz(wo1.x, wo1.y), pkrtz(wo1.z, wo1.w));
        *(uint2*)&Wop[e1 * 36 + (k1 >> 1)] = wb;
    }
    __syncthreads();

    #pragma unroll
    for (int t = 0; t < 8; t++) {
        int fi = tid + t * 512;
        int f = fi >> 4, k0 = (fi & 15) * 4;
        uint2 w2 = make_uint2(pkrtz(w1r[t].x, w1r[t].y), pkrtz(w1r[t].z, w1r[t].w));
        *(uint2*)&W1p[f * 36 + (k0 >> 1)] = w2;
    }

    if (wave < 2) {
        const int colo = wave * 32 + (lane & 31);
        f32x16 acc = z16;
        #pragma unroll
        for (int kk = 0; kk < 4; kk++) {
            half8_t a = __builtin_bit_cast(half8_t,
                *(const uint4*)&Atp[(lane & 31) * 36 + kk * 8 + h * 4]);
            half8_t b = __builtin_bit_cast(half8_t,
                *(const uint4*)&Wop[colo * 36 + kk * 8 + h * 4]);
            acc = __builtin_amdgcn_mfma_f32_32x32x16_f16(a, b, acc, 0, 0, 0);
        }
        float bov = bo[colo];
        #pragma unroll
        for (int reg = 0; reg < 16; reg++) {
            int rr = (reg & 3) + 8 * (reg >> 2) + 4 * h;
            Yf[rr * 68 + colo] = acc[reg] + bov;
        }
    }
    __syncthreads();

    float x1v[4];
    {
        float4 yv = *(const float4*)&Yf[mrow * 68 + c0];
        float vv[4] = {xv.x + yv.x, xv.y + yv.y, xv.z + yv.z, xv.w + yv.w};
        float s1 = vv[0] + vv[1] + vv[2] + vv[3];
        float s2 = vv[0]*vv[0] + vv[1]*vv[1] + vv[2]*vv[2] + vv[3]*vv[3];
        #pragma unroll
        for (int m = 1; m <= 8; m <<= 1) {
            s1 += __shfl_xor(s1, m);
            s2 += __shfl_xor(s2, m);
        }
        float mean = s1 * 0.015625f;
        float rstd = rsqrtf(s2 * 0.015625f - mean * mean + 1e-5f);
        float4 g14 = *(const float4*)&g1[c0];
        float4 be14 = *(const float4*)&be1[c0];
        float gg[4] = {g14.x, g14.y, g14.z, g14.w};
        float eb[4] = {be14.x, be14.y, be14.z, be14.w};
        float cth = __cosf(*theta_ffn);
        float qv[4];
        #pragma unroll
        for (int j = 0; j < 4; j++) {
            x1v[j] = (vv[j] - mean) * rstd * gg[j] + eb[j];
            qv[j] = __cosf(x1v[j]) * cth;
        }
        uint2 q2 = make_uint2(pkrtz(qv[0], qv[1]), pkrtz(qv[2], qv[3]));
        *(uint2*)&qoutp[mrow * 36 + (c0 >> 1)] = q2;
    }
    __syncthreads();

    float4 w2r[8];
    #pragma unroll
    for (int t = 0; t < 8; t++) w2r[t] = ((const float4*)W2)[tid + t * 512];

    {
        const int fl = lane & 31;
        f32x16 acc = z16;
        #pragma unroll
        for (int kk = 0; kk < 4; kk++) {
            half8_t a = __builtin_bit_cast(half8_t,
                *(const uint4*)&W1p[(wave * 32 + fl) * 36 + kk * 8 + h * 4]);
            half8_t b = __builtin_bit_cast(half8_t,
                *(const uint4*)&qoutp[fl * 36 + kk * 8 + h * 4]);
            acc = __builtin_amdgcn_mfma_f32_32x32x16_f16(a, b, acc, 0, 0, 0);
        }
        const int row = lane & 31;
        #pragma unroll
        for (int q = 0; q < 4; q++) {
            int fb = wave * 32 + 8 * q + 4 * h;
            float4 b1v = *(const float4*)&b1[fb];
            float h0 = fmaxf(acc[4*q+0] + b1v.x, 0.f);
            float h1 = fmaxf(acc[4*q+1] + b1v.y, 0.f);
            float h2 = fmaxf(acc[4*q+2] + b1v.z, 0.f);
            float h3 = fmaxf(acc[4*q+3] + b1v.w, 0.f);
            uint2 hp = make_uint2(pkrtz(h0, h1), pkrtz(h2, h3));
            *(uint2*)&hrowp[row * 132 + (fb >> 1)] = hp;
        }
    }
    __syncthreads();

    #pragma unroll
    for (int t = 0; t < 8; t++) {
        int fi = tid + t * 512;
        int e = fi >> 6, k0 = (fi & 63) * 4;
        uint2 w2 = make_uint2(pkrtz(w2r[t].x, w2r[t].y), pkrtz(w2r[t].z, w2r[t].w));
        *(uint2*)&W2p[e * 132 + (k0 >> 1)] = w2;
    }
    __syncthreads();

    if (wave < 2) {
        const int colo = wave * 32 + (lane & 31);
        f32x16 acc = z16;
        #pragma unroll
        for (int kk = 0; kk < 16; kk++) {
            half8_t a = __builtin_bit_cast(half8_t,
                *(const uint4*)&hrowp[(lane & 31) * 132 + kk * 8 + h * 4]);
            half8_t b = __builtin_bit_cast(half8_t,
                *(const uint4*)&W2p[colo * 132 + kk * 8 + h * 4]);
            acc = __builtin_amdgcn_mfma_f32_32x32x16_f16(a, b, acc, 0, 0, 0);
        }
        float b2v = b2[colo];
        float* Ydst = wave ? Y2b : Y2a;
        const int cl = lane & 31;
        #pragma unroll
        for (int reg = 0; reg < 16; reg++) {
            int rr = (reg & 3) + 8 * (reg >> 2) + 4 * h;
            Ydst[rr * 36 + cl] = acc[reg] + b2v;
        }
    }
    __syncthreads();

    {
        float4 fv = (c0 < 32) ? *(const float4*)&Y2a[mrow * 36 + c0]
                              : *(const float4*)&Y2b[mrow * 36 + (c0 - 32)];
        float vv[4] = {x1v[0] + fv.x, x1v[1] + fv.y, x1v[2] + fv.z, x1v[3] + fv.w};
        float s1 = vv[0] + vv[1] + vv[2] + vv[3];
        float s2 = vv[0]*vv[0] + vv[1]*vv[1] + vv[2]*vv[2] + vv[3]*vv[3];
        #pragma unroll
        for (int m = 1; m <= 8; m <<= 1) {
            s1 += __shfl_xor(s1, m);
            s2 += __shfl_xor(s2, m);
        }
        float mean = s1 * 0.015625f;
        float rstd = rsqrtf(s2 * 0.015625f - mean * mean + 1e-5f);
        float4 g24 = *(const float4*)&g2[c0];
        float4 be24 = *(const float4*)&be2[c0];
        float4 o;
        o.x = (vv[0] - mean) * rstd * g24.x + be24.x;
        o.y = (vv[1] - mean) * rstd * g24.y + be24.y;
        o.z = (vv[2] - mean) * rstd * g24.z + be24.z;
        o.w = (vv[3] - mean) * rstd * g24.w + be24.w;
        *(float4*)(outp + (size_t)(n0 + mrow) * 64 + c0) = o;
    }
}

// ---------------------------------------------------------------------------
extern "C" void kernel_launch(void* const* d_in, const int* in_sizes, int n_in,
                              void* d_out, int out_size, void* d_ws, size_t ws_size,
                              hipStream_t stream)
{
    const float* x   = (const float*)d_in[0];
    const float* Wq  = (const float*)d_in[1];
    const float* bq  = (const float*)d_in[2];
    const float* Wk  = (const float*)d_in[3];
    const float* bk  = (const float*)d_in[4];
    const float* Wv  = (const float*)d_in[5];
    const float* bv  = (const float*)d_in[6];
    const float* Wo  = (const float*)d_in[7];
    const float* bo  = (const float*)d_in[8];
    const float* tha = (const float*)d_in[9];
    const float* thf = (const float*)d_in[10];
    const float* W1  = (const float*)d_in[11];
    const float* b1  = (const float*)d_in[12];
    const float* W2  = (const float*)d_in[13];
    const float* b2  = (const float*)d_in[14];
    const float* g1  = (const float*)d_in[15];
    const float* be1 = (const float*)d_in[16];
    const float* g2  = (const float*)d_in[17];
    const float* be2 = (const float*)d_in[18];

    // workspace: qb(2M) kb(2M) vb(2M) attn(4M)
    char* wsb = (char*)d_ws;
    unsigned short* qbp = (unsigned short*)(wsb);
    unsigned short* kbp = (unsigned short*)(wsb + (2u << 20));
    unsigned short* vbp = (unsigned short*)(wsb + (4u << 20));
    float* attn = (float*)(wsb + (6u << 20));

    qkv_kernel<<<256, 512, 0, stream>>>(x, Wq, bq, Wk, bk, Wv, bv, tha, qbp, kbp, vbp);
    attn_kernel<<<1024, 256, 0, stream>>>(qbp, kbp, vbp, attn);
    tail_kernel<<<512, 512, 0, stream>>>(attn, x, Wo, bo, g1, be1, thf,
                                         W1, b1, W2, b2, g2, be2, (float*)d_out);
}